// Round 9
// baseline (1104.608 us; speedup 1.0000x reference)
//
#include <hip/hip_runtime.h>
#include <cstdint>

// ---------------- problem constants ----------------
#define BB   128
#define TT   100
#define HID  512

typedef __attribute__((ext_vector_type(4))) float f32x4;
typedef __attribute__((ext_vector_type(2))) float f32x2;
typedef __attribute__((ext_vector_type(8))) short short8;
typedef __attribute__((ext_vector_type(4))) short short4_t;
typedef unsigned long long ull;

__device__ __forceinline__ short f2bf(float x) {            // RNE fp32 -> bf16
  unsigned u = __float_as_uint(x);
  unsigned r = (u + 0x7fffu + ((u >> 16) & 1u)) >> 16;
  return (short)r;
}
__device__ __forceinline__ float bf2f(short s) {
  return __uint_as_float(((unsigned)(unsigned short)s) << 16);
}

// ==================== weight prep: fp32 -> bf16 hi/lo planes ====================
__global__ __launch_bounds__(256) void wsplit_k(const float* __restrict__ w,
                                                unsigned short* __restrict__ hi,
                                                unsigned short* __restrict__ lo,
                                                int nq) {
  int i = blockIdx.x * 256 + threadIdx.x;
  const int stride = gridDim.x * 256;
  for (; i < nq; i += stride) {
    f32x4 v = *(const f32x4*)(w + 4 * (long)i);
    short4_t h, l;
    #pragma unroll
    for (int c = 0; c < 4; c++) {
      short hh = f2bf(v[c]); h[c] = hh; l[c] = f2bf(v[c] - bf2f(hh));
    }
    *(short4_t*)(hi + 4 * (long)i) = h;
    *(short4_t*)(lo + 4 * (long)i) = l;
  }
}

// ==================== encoder (unchanged from R9) ====================

__global__ __launch_bounds__(192) void conv1_k(const float* __restrict__ in,
                                               const float* __restrict__ w,
                                               const float* __restrict__ bias,
                                               float* __restrict__ out) {
  const int b = blockIdx.x / 24, oy = blockIdx.x % 24;
  __shared__ __attribute__((aligned(16))) float in_s[3][5][76]; // p = ix+2
  __shared__ __attribute__((aligned(16))) float ws[64][76];     // padded rows
  const int tid = threadIdx.x;
  for (int i = tid; i < 3 * 5 * 76; i += 192) {
    int ic = i / 380, rem = i % 380, r = rem / 76, p = rem % 76;
    int iy = oy * 3 + r - 2, ix = p - 2;
    in_s[ic][r][p] = (iy >= 0 && iy < 72 && ix >= 0 && ix < 72)
                       ? in[((long)(b * 3 + ic) * 72 + iy) * 72 + ix] : 0.f;
  }
  for (int i = tid; i < 64 * 75; i += 192) ws[i / 75][i % 75] = w[i];
  __syncthreads();

  const int ox2 = tid % 12;           // ox pair: ox = 2*ox2, 2*ox2+1
  const int og = tid / 12;            // 0..15
  float strip[15][8];
  #pragma unroll
  for (int ic = 0; ic < 3; ic++)
    #pragma unroll
    for (int ky = 0; ky < 5; ky++) {
      const float* bp = &in_s[ic][ky][6 * ox2];
      #pragma unroll
      for (int h = 0; h < 4; h++) {
        f32x2 u = *(const f32x2*)(bp + 2 * h);
        strip[ic * 5 + ky][2 * h] = u[0];
        strip[ic * 5 + ky][2 * h + 1] = u[1];
      }
    }

  #pragma unroll
  for (int j = 0; j < 4; j++) {
    const int oc = og + 16 * j;
    float s0 = bias[oc], s1 = bias[oc];
    const float* wrow = ws[oc];
    #pragma unroll
    for (int k4 = 0; k4 < 18; k4++) {
      f32x4 wq = *(const f32x4*)(wrow + 4 * k4);
      #pragma unroll
      for (int q = 0; q < 4; q++) {
        const int k = 4 * k4 + q, i5 = k / 5, kx = k % 5;
        s0 += strip[i5][kx] * wq[q];
        s1 += strip[i5][kx + 3] * wq[q];
      }
    }
    s0 += strip[14][2] * wrow[72]; s1 += strip[14][5] * wrow[72];
    s0 += strip[14][3] * wrow[73]; s1 += strip[14][6] * wrow[73];
    s0 += strip[14][4] * wrow[74]; s1 += strip[14][7] * wrow[74];
    long o = ((long)(b * 64 + oc) * 24 + oy) * 24 + 2 * ox2;
    out[o] = fmaxf(s0, 0.f);
    out[o + 1] = fmaxf(s1, 0.f);
  }
}

template <int IC, int IH, int IW, int OC, int OH, int OW>
__global__ void convs3(const float* __restrict__ in, const float* __restrict__ w,
                       const float* __restrict__ bias, float* __restrict__ out) {
  const int b = blockIdx.x / OH, oy = blockIdx.x % OH;
  constexpr int PW = 3 * OW;           // padded width; p = ox*3+kx in [0, 3*OW-1]
  constexpr int NT = (OC / 2) * OW;    // threads
  __shared__ __attribute__((aligned(16))) float in_s[8][3][PW];
  __shared__ __attribute__((aligned(16))) float w_s[OC][100];  // [oc][ic*12 + j]
  const int tid = threadIdx.x;
  const int oc = tid / OW, ox = tid % OW;     // oc in 0..OC/2-1
  float s0 = bias[oc], s1 = bias[oc + OC / 2];
  for (int cc = 0; cc < IC; cc += 8) {
    __syncthreads();
    for (int i = tid; i < 8 * 3 * PW; i += NT) {
      int ic = i / (3 * PW), r = (i / PW) % 3, p = i % PW;
      int iy = oy * 3 - 2 + r, ix = p - 2;
      in_s[ic][r][p] = (iy >= 0 && iy < IH && ix >= 0 && ix < IW)
                         ? in[((long)(b * IC + cc + ic) * IH + iy) * IW + ix] : 0.f;
    }
    for (int i = tid; i < OC * 8 * 9; i += NT) {
      int o = i / 72, r = i % 72;
      w_s[o][(r / 9) * 12 + (r % 9)] = w[(long)(o * IC + cc + r / 9) * 9 + r % 9];
    }
    __syncthreads();
    #pragma unroll
    for (int ic = 0; ic < 8; ic++) {
      const float* wr0 = &w_s[oc][ic * 12];
      const float* wr1 = &w_s[oc + OC / 2][ic * 12];
      f32x4 wa = *(const f32x4*)wr0, wb = *(const f32x4*)(wr0 + 4);
      f32x4 va = *(const f32x4*)wr1, vb = *(const f32x4*)(wr1 + 4);
      float wA[9] = {wa[0], wa[1], wa[2], wa[3], wb[0], wb[1], wb[2], wb[3], wr0[8]};
      float wB[9] = {va[0], va[1], va[2], va[3], vb[0], vb[1], vb[2], vb[3], wr1[8]};
      #pragma unroll
      for (int ky = 0; ky < 3; ky++)
        #pragma unroll
        for (int kx = 0; kx < 3; kx++) {
          float iv = in_s[ic][ky][ox * 3 + kx];
          s0 += iv * wA[ky * 3 + kx];
          s1 += iv * wB[ky * 3 + kx];
        }
    }
  }
  out[((long)(b * OC + oc) * OH + oy) * OW + ox] = fmaxf(s0, 0.f);
  out[((long)(b * OC + oc + OC / 2) * OH + oy) * OW + ox] = fmaxf(s1, 0.f);
}

template <int K, int N, bool RELU>
__global__ __launch_bounds__(128) void fc_mfma(const float* __restrict__ A,
                                               const unsigned short* __restrict__ wh,
                                               const unsigned short* __restrict__ wl,
                                               const float* __restrict__ bias,
                                               float* __restrict__ C) {
  const int nb = N / 32;
  const int rb = (blockIdx.x / nb) * 16, cb = (blockIdx.x % nb) * 32;
  __shared__ __attribute__((aligned(16))) short A_hi[16][K + 8];
  __shared__ __attribute__((aligned(16))) short A_lo[16][K + 8];
  const int tid = threadIdx.x;
  const int wv = tid >> 6, lane = tid & 63, n16 = lane & 15, quad = lane >> 4;

  for (int i = tid; i < 16 * (K / 4); i += 128) {
    int row = i / (K / 4), q = i % (K / 4);
    f32x4 v = *(const f32x4*)(A + (long)(rb + row) * K + 4 * q);
    short4_t sh, sl;
    #pragma unroll
    for (int c = 0; c < 4; c++) {
      short hh = f2bf(v[c]); sh[c] = hh; sl[c] = f2bf(v[c] - bf2f(hh));
    }
    *(short4_t*)&A_hi[row][4 * q] = sh;
    *(short4_t*)&A_lo[row][4 * q] = sl;
  }
  __syncthreads();

  const int col = cb + wv * 16 + n16;
  f32x4 a0 = {0.f, 0.f, 0.f, 0.f}, a1 = a0, a2 = a0;
  constexpr int NP = K / 512;
  #pragma unroll 1
  for (int p = 0; p < NP; p++) {
    short8 fh[16], fl[16];
    const unsigned short* wb0 = wh + (long)col * K + p * 512 + quad * 8;
    const unsigned short* wb1 = wl + (long)col * K + p * 512 + quad * 8;
    #pragma unroll
    for (int ks = 0; ks < 16; ks++) {
      fh[ks] = *(const short8*)(wb0 + ks * 32);
      fl[ks] = *(const short8*)(wb1 + ks * 32);
    }
    #pragma unroll
    for (int ks = 0; ks < 16; ks++) {
      short8 ah = *(const short8*)&A_hi[n16][p * 512 + ks * 32 + quad * 8];
      short8 al = *(const short8*)&A_lo[n16][p * 512 + ks * 32 + quad * 8];
      a0 = __builtin_amdgcn_mfma_f32_16x16x32_bf16(ah, fh[ks], a0, 0, 0, 0);
      a1 = __builtin_amdgcn_mfma_f32_16x16x32_bf16(al, fh[ks], a1, 0, 0, 0);
      a2 = __builtin_amdgcn_mfma_f32_16x16x32_bf16(ah, fl[ks], a2, 0, 0, 0);
    }
  }
  const float bv = bias[col];
  #pragma unroll
  for (int r = 0; r < 4; r++) {          // C layout: col=lane&15, row=quad*4+r
    float v = a0[r] + a1[r] + a2[r] + bv;
    if (RELU) v = fmaxf(v, 0.f);
    C[(long)(rb + quad * 4 + r) * N + col] = v;
  }
}

// ==================== persistent GRU ====================
// R13 = R6's halved-consumer structure with the spill bug fixed.
// grid 128 = 8 bg x 16 hg (32 dims each); 384 thr = 6 waves =
// {2 hidden sub-tiles} x {3 accumulation chains: ah*whi, al*whi, ah*wlo}.
// __launch_bounds__(384, 1): VGPR cap 256 (R6's (384,2) capped at 128 ->
// wfrag spilled to scratch; that run never tested the theory).
// Exchange = R4-VERBATIM (the measured-361 version): fp32 h through `out`
// with agent-scope stores, fetch_add barrier (target 16*(t+1)), coalesced
// 8B reload + consumer-side bf16 hi/lo convert into LDS.
// hprev carried in elementwise-thread registers (R10/R11/R12-verified).
__global__ __launch_bounds__(384, 1) void gru_k(
    const float* __restrict__ actions, const float* __restrict__ w_ih,
    const float* __restrict__ w_hh, const float* __restrict__ b_ih,
    const float* __restrict__ b_hh, const float* __restrict__ h0,
    float* __restrict__ out, float* __restrict__ hT, unsigned* __restrict__ bar) {
  const int bg = blockIdx.x >> 4;   // 0..7
  const int hg = blockIdx.x & 15;   // 0..15  (32-dim slice)
  const int tid = threadIdx.x;
  const int wv = tid >> 6;          // 0..5
  const int ch = wv % 3;            // chain: 0 = ah*whi, 1 = al*whi, 2 = ah*wlo
  const int sub = wv / 3;           // hidden sub-tile: dims hg*32 + sub*16 + n16
  const int lane = tid & 63;
  const int n16 = lane & 15;
  const int quad = lane >> 4;

  __shared__ short h_hi[16][520];   // +8 pad: 2-way-max LDS banking for b128 reads
  __shared__ short h_lo[16][520];
  __shared__ float act_s[16][2 * TT];
  __shared__ float gh_s[3][16][97];     // [chain][m][gate*32 + n], pad 97
  __shared__ float bih_s[96], bhh_s[96], wih0_s[96], wih1_s[96];

  // ---- per-lane w_hh B-fragments: all 3 gates of this wave's chain operand ----
  short8 wfrag[3][16];
  {
    #pragma unroll
    for (int g = 0; g < 3; g++) {
      const int grow = g * HID + hg * 32 + sub * 16 + n16;
      const float* wr = w_hh + (long)grow * HID + quad * 8;
      #pragma unroll
      for (int ks = 0; ks < 16; ks++) {
        f32x4 v0 = *(const f32x4*)(wr + ks * 32);
        f32x4 v1 = *(const f32x4*)(wr + ks * 32 + 4);
        short8 f;
        #pragma unroll
        for (int j = 0; j < 4; j++) {
          float x0 = v0[j], x1 = v1[j];
          short hh0 = f2bf(x0), hh1 = f2bf(x1);
          f[j]     = (ch == 2) ? f2bf(x0 - bf2f(hh0)) : hh0;
          f[j + 4] = (ch == 2) ? f2bf(x1 - bf2f(hh1)) : hh1;
        }
        wfrag[g][ks] = f;
      }
    }
  }
  for (int i = tid; i < 96; i += 384) {
    int row = (i >> 5) * HID + hg * 32 + (i & 31);
    bih_s[i] = b_ih[row];
    bhh_s[i] = b_hh[row];
    wih0_s[i] = w_ih[row * 2];
    wih1_s[i] = w_ih[row * 2 + 1];
  }
  for (int i = tid; i < 16 * 2 * TT; i += 384) {
    int m = i / (2 * TT), r = i % (2 * TT);
    act_s[m][r] = actions[(long)(bg * 16 + m) * (2 * TT) + r];
  }
  // h0 -> LDS (bf16 hi/lo)
  for (int i = tid; i < 2048; i += 384) {
    int m = i >> 7, k4 = (i & 127) << 2;
    f32x4 v = *(const f32x4*)(h0 + (long)(bg * 16 + m) * HID + k4);
    short4_t sh, sl;
    #pragma unroll
    for (int c2 = 0; c2 < 4; c2++) {
      short hh = f2bf(v[c2]); sh[c2] = hh; sl[c2] = f2bf(v[c2] - bf2f(hh));
    }
    *(short4_t*)&h_hi[m][k4] = sh;
    *(short4_t*)&h_lo[m][k4] = sl;
  }
  // hprev in registers for the elementwise threads
  float hp0 = 0.f, hp1 = 0.f;
  if (tid < 256) {
    const int m = tid >> 4, n0 = (tid & 15) << 1;
    f32x2 u = *(const f32x2*)(h0 + (long)(bg * 16 + m) * HID + hg * 32 + n0);
    hp0 = u[0]; hp1 = u[1];
  }
  __syncthreads();

  unsigned* my_bar = bar + bg * 32;  // 128B-spaced per-group counters
  short (*hp)[520] = (ch == 1) ? h_lo : h_hi;   // this wave's A-operand plane

  #pragma unroll 1
  for (int t = 0; t < TT; t++) {
    // ---- gh: this wave's chain+sub, all 3 gate tiles (16 b128 reads/wave) ----
    f32x4 a0 = {0.f, 0.f, 0.f, 0.f}, a1 = a0, a2 = a0;   // gates r, z, n
    #pragma unroll
    for (int ks = 0; ks < 16; ks++) {
      short8 av = *(const short8*)&hp[n16][ks * 32 + quad * 8];
      a0 = __builtin_amdgcn_mfma_f32_16x16x32_bf16(av, wfrag[0][ks], a0, 0, 0, 0);
      a1 = __builtin_amdgcn_mfma_f32_16x16x32_bf16(av, wfrag[1][ks], a1, 0, 0, 0);
      a2 = __builtin_amdgcn_mfma_f32_16x16x32_bf16(av, wfrag[2][ks], a2, 0, 0, 0);
    }
    #pragma unroll
    for (int r = 0; r < 4; r++) {          // C layout: col=lane&15, row=quad*4+r
      gh_s[ch][quad * 4 + r][sub * 16 + n16]      = a0[r];
      gh_s[ch][quad * 4 + r][32 + sub * 16 + n16] = a1[r];
      gh_s[ch][quad * 4 + r][64 + sub * 16 + n16] = a2[r];
    }
    __syncthreads();

    // ---- elementwise gates + h update; 256 threads x 2 hidden dims ----
    if (tid < 256) {
      const int m = tid >> 4;
      const int n0 = (tid & 15) << 1;
      const float x0 = act_s[m][2 * t], x1 = act_s[m][2 * t + 1];
      float hy[2];
      #pragma unroll
      for (int q = 0; q < 2; q++) {
        int n = n0 + q;
        float hr = gh_s[0][m][n]      + gh_s[1][m][n]      + gh_s[2][m][n]      + bhh_s[n];
        float hz = gh_s[0][m][32 + n] + gh_s[1][m][32 + n] + gh_s[2][m][32 + n] + bhh_s[32 + n];
        float hn = gh_s[0][m][64 + n] + gh_s[1][m][64 + n] + gh_s[2][m][64 + n] + bhh_s[64 + n];
        float ir = x0 * wih0_s[n]      + x1 * wih1_s[n]      + bih_s[n];
        float iz = x0 * wih0_s[32 + n] + x1 * wih1_s[32 + n] + bih_s[32 + n];
        float in_ = x0 * wih0_s[64 + n] + x1 * wih1_s[64 + n] + bih_s[64 + n];
        float rg = 1.f / (1.f + __expf(-(ir + hr)));
        float zg = 1.f / (1.f + __expf(-(iz + hz)));
        float nx = in_ + rg * hn;
        float ng = 1.f - 2.f / (__expf(2.f * nx) + 1.f);   // tanh
        float hprev = q ? hp1 : hp0;
        hy[q] = ng + zg * (hprev - ng);
      }
      hp0 = hy[0]; hp1 = hy[1];
      ull pack = (ull)__float_as_uint(hy[0]) |
                 ((ull)__float_as_uint(hy[1]) << 32);
      // device-coherent packed store (bypasses non-coherent L1/L2)
      __hip_atomic_store(
          (ull*)&out[((long)(bg * 16 + m) * TT + t) * HID + hg * 32 + n0],
          pack, __ATOMIC_RELAXED, __HIP_MEMORY_SCOPE_AGENT);
      if (t == TT - 1)
        *(ull*)&hT[(long)(bg * 16 + m) * HID + hg * 32 + n0] = pack;
    }
    __syncthreads();   // drains vmcnt(0): slice stores are device-visible

    if (t < TT - 1) {
      if (tid == 0) {
        const unsigned target = 16u * (unsigned)(t + 1);
        unsigned prev = __hip_atomic_fetch_add(my_bar, 1u, __ATOMIC_RELAXED,
                                               __HIP_MEMORY_SCOPE_AGENT);
        if (prev + 1u < target) {
          while (__hip_atomic_load(my_bar, __ATOMIC_RELAXED,
                                   __HIP_MEMORY_SCOPE_AGENT) < target)
            __builtin_amdgcn_s_sleep(1);
        }
      }
      __syncthreads();
      // ---- pipelined reload: 10 uniform 8B loads/thread + 256-thread tail ----
      // (4096 8B-chunks = 16 rows x 256; issue ALL loads, then convert)
      ull vbuf[11];
      #pragma unroll
      for (int u = 0; u < 10; u++) {
        int i = tid + u * 384;
        int m = i >> 8, j = (i & 255) << 1;
        vbuf[u] = __hip_atomic_load(
            (const ull*)(out + ((long)(bg * 16 + m) * TT + t) * HID + j),
            __ATOMIC_RELAXED, __HIP_MEMORY_SCOPE_AGENT);
      }
      if (tid < 256) {
        int i = 3840 + tid;
        int m = i >> 8, j = (i & 255) << 1;
        vbuf[10] = __hip_atomic_load(
            (const ull*)(out + ((long)(bg * 16 + m) * TT + t) * HID + j),
            __ATOMIC_RELAXED, __HIP_MEMORY_SCOPE_AGENT);
      }
      #pragma unroll
      for (int u = 0; u < 10; u++) {
        int i = tid + u * 384;
        int m = i >> 8, j = (i & 255) << 1;
        ull v = vbuf[u];
        float f0 = __uint_as_float((unsigned)v);
        float f1 = __uint_as_float((unsigned)(v >> 32));
        short s0 = f2bf(f0);
        h_hi[m][j] = s0; h_lo[m][j] = f2bf(f0 - bf2f(s0));
        short s1 = f2bf(f1);
        h_hi[m][j + 1] = s1; h_lo[m][j + 1] = f2bf(f1 - bf2f(s1));
      }
      if (tid < 256) {
        int i = 3840 + tid;
        int m = i >> 8, j = (i & 255) << 1;
        ull v = vbuf[10];
        float f0 = __uint_as_float((unsigned)v);
        float f1 = __uint_as_float((unsigned)(v >> 32));
        short s0 = f2bf(f0);
        h_hi[m][j] = s0; h_lo[m][j] = f2bf(f0 - bf2f(s0));
        short s1 = f2bf(f1);
        h_hi[m][j + 1] = s1; h_lo[m][j + 1] = f2bf(f1 - bf2f(s1));
      }
      __syncthreads();
    }
  }
}

// ==================== launch ====================
extern "C" void kernel_launch(void* const* d_in, const int* in_sizes, int n_in,
                              void* d_out, int out_size, void* d_ws, size_t ws_size,
                              hipStream_t stream) {
  const float* images  = (const float*)d_in[0];
  const float* actions = (const float*)d_in[1];
  const float* cw1 = (const float*)d_in[2];
  const float* cb1 = (const float*)d_in[3];
  const float* cw2 = (const float*)d_in[4];
  const float* cb2 = (const float*)d_in[5];
  const float* cw3 = (const float*)d_in[6];
  const float* cb3 = (const float*)d_in[7];
  const float* fw1 = (const float*)d_in[8];
  const float* fb1 = (const float*)d_in[9];
  const float* fw2 = (const float*)d_in[10];
  const float* fb2 = (const float*)d_in[11];
  const float* fw3 = (const float*)d_in[12];
  const float* fb3 = (const float*)d_in[13];
  const float* w_ih = (const float*)d_in[14];
  const float* w_hh = (const float*)d_in[15];
  const float* b_ih = (const float*)d_in[16];
  const float* b_hh = (const float*)d_in[17];

  char* ws = (char*)d_ws;
  unsigned* bar = (unsigned*)ws;                 // 1 KB of barrier counters
  float* a1 = (float*)(ws + 1024);               // [128,64,24,24]
  float* a2 = a1 + (long)128 * 64 * 576;         // [128,64,9,9]
  float* a3 = a2 + (long)128 * 64 * 81;          // [128,1024] flat
  float* f1 = a3 + (long)128 * 1024;             // [128,1024]
  float* f2 = f1 + (long)128 * 1024;             // [128,512]
  float* h0 = f2 + (long)128 * 512;              // [128,512]
  // bf16 hi/lo planes of fc weights (filled by wsplit_k):
  unsigned short* wfh1 = (unsigned short*)(h0 + 65536);   // 1024*1024
  unsigned short* wfl1 = wfh1 + (long)1048576;
  unsigned short* wfh2 = wfl1 + (long)1048576;            // 512*1024
  unsigned short* wfl2 = wfh2 + (long)524288;
  unsigned short* wfh3 = wfl2 + (long)524288;             // 512*512
  unsigned short* wfl3 = wfh3 + (long)262144;

  float* out = (float*)d_out;                    // [128,100,512]
  float* hT  = out + (long)BB * TT * HID;        // [128,512]

  hipMemsetAsync(bar, 0, 1024, stream);
  wsplit_k<<<256, 256, 0, stream>>>(fw1, wfh1, wfl1, 262144);
  wsplit_k<<<128, 256, 0, stream>>>(fw2, wfh2, wfl2, 131072);
  wsplit_k<<<64, 256, 0, stream>>>(fw3, wfh3, wfl3, 65536);
  conv1_k<<<128 * 24, 192, 0, stream>>>(images, cw1, cb1, a1);
  convs3<64, 24, 24, 64, 9, 9><<<128 * 9, 288, 0, stream>>>(a1, cw2, cb2, a2);
  convs3<64, 9, 9, 64, 4, 4><<<128 * 4, 128, 0, stream>>>(a2, cw3, cb3, a3);
  fc_mfma<1024, 1024, true><<<256, 128, 0, stream>>>(a3, wfh1, wfl1, fb1, f1);
  fc_mfma<1024, 512, true><<<128, 128, 0, stream>>>(f1, wfh2, wfl2, fb2, f2);
  fc_mfma<512, 512, false><<<128, 128, 0, stream>>>(f2, wfh3, wfl3, fb3, h0);
  gru_k<<<128, 384, 0, stream>>>(actions, w_ih, w_hh, b_ih, b_hh, h0, out, hT, bar);
}

// Round 10
// 720.261 us; speedup vs baseline: 1.5336x; 1.5336x over previous
//
#include <hip/hip_runtime.h>
#include <cstdint>

// ---------------- problem constants ----------------
#define BB   128
#define TT   100
#define HID  512

typedef __attribute__((ext_vector_type(4))) float f32x4;
typedef __attribute__((ext_vector_type(2))) float f32x2;
typedef __attribute__((ext_vector_type(8))) short short8;
typedef __attribute__((ext_vector_type(4))) short short4_t;
typedef unsigned long long ull;

__device__ __forceinline__ short f2bf(float x) {            // RNE fp32 -> bf16
  unsigned u = __float_as_uint(x);
  unsigned r = (u + 0x7fffu + ((u >> 16) & 1u)) >> 16;
  return (short)r;
}
__device__ __forceinline__ float bf2f(short s) {
  return __uint_as_float(((unsigned)(unsigned short)s) << 16);
}
__device__ __forceinline__ ull aload8(const void* p) {
  return __hip_atomic_load((const ull*)p, __ATOMIC_RELAXED, __HIP_MEMORY_SCOPE_AGENT);
}

// ==================== weight prep: fp32 -> bf16 hi/lo (3 arrays, 1 kernel) ====
__global__ __launch_bounds__(256) void wsplit_all(
    const float* __restrict__ w1, const float* __restrict__ w2,
    const float* __restrict__ w3, unsigned short* __restrict__ h1,
    unsigned short* __restrict__ l1, unsigned short* __restrict__ h2,
    unsigned short* __restrict__ l2, unsigned short* __restrict__ h3,
    unsigned short* __restrict__ l3) {
  int i = blockIdx.x * 256 + threadIdx.x;
  const int stride = gridDim.x * 256;
  for (; i < 458752; i += stride) {
    const float* src; unsigned short *ph, *pl; int j;
    if (i < 262144)      { src = w1; ph = h1; pl = l1; j = i; }
    else if (i < 393216) { src = w2; ph = h2; pl = l2; j = i - 262144; }
    else                 { src = w3; ph = h3; pl = l3; j = i - 393216; }
    f32x4 v = *(const f32x4*)(src + 4 * (long)j);
    short4_t h, l;
    #pragma unroll
    for (int c = 0; c < 4; c++) {
      short hh = f2bf(v[c]); h[c] = hh; l[c] = f2bf(v[c] - bf2f(hh));
    }
    *(short4_t*)(ph + 4 * (long)j) = h;
    *(short4_t*)(pl + 4 * (long)j) = l;
  }
}

// ==================== encoder (unchanged from R9) ====================

__global__ __launch_bounds__(192) void conv1_k(const float* __restrict__ in,
                                               const float* __restrict__ w,
                                               const float* __restrict__ bias,
                                               float* __restrict__ out) {
  const int b = blockIdx.x / 24, oy = blockIdx.x % 24;
  __shared__ __attribute__((aligned(16))) float in_s[3][5][76]; // p = ix+2
  __shared__ __attribute__((aligned(16))) float ws[64][76];     // padded rows
  const int tid = threadIdx.x;
  for (int i = tid; i < 3 * 5 * 76; i += 192) {
    int ic = i / 380, rem = i % 380, r = rem / 76, p = rem % 76;
    int iy = oy * 3 + r - 2, ix = p - 2;
    in_s[ic][r][p] = (iy >= 0 && iy < 72 && ix >= 0 && ix < 72)
                       ? in[((long)(b * 3 + ic) * 72 + iy) * 72 + ix] : 0.f;
  }
  for (int i = tid; i < 64 * 75; i += 192) ws[i / 75][i % 75] = w[i];
  __syncthreads();

  const int ox2 = tid % 12;           // ox pair: ox = 2*ox2, 2*ox2+1
  const int og = tid / 12;            // 0..15
  float strip[15][8];
  #pragma unroll
  for (int ic = 0; ic < 3; ic++)
    #pragma unroll
    for (int ky = 0; ky < 5; ky++) {
      const float* bp = &in_s[ic][ky][6 * ox2];
      #pragma unroll
      for (int h = 0; h < 4; h++) {
        f32x2 u = *(const f32x2*)(bp + 2 * h);
        strip[ic * 5 + ky][2 * h] = u[0];
        strip[ic * 5 + ky][2 * h + 1] = u[1];
      }
    }

  #pragma unroll
  for (int j = 0; j < 4; j++) {
    const int oc = og + 16 * j;
    float s0 = bias[oc], s1 = bias[oc];
    const float* wrow = ws[oc];
    #pragma unroll
    for (int k4 = 0; k4 < 18; k4++) {
      f32x4 wq = *(const f32x4*)(wrow + 4 * k4);
      #pragma unroll
      for (int q = 0; q < 4; q++) {
        const int k = 4 * k4 + q, i5 = k / 5, kx = k % 5;
        s0 += strip[i5][kx] * wq[q];
        s1 += strip[i5][kx + 3] * wq[q];
      }
    }
    s0 += strip[14][2] * wrow[72]; s1 += strip[14][5] * wrow[72];
    s0 += strip[14][3] * wrow[73]; s1 += strip[14][6] * wrow[73];
    s0 += strip[14][4] * wrow[74]; s1 += strip[14][7] * wrow[74];
    long o = ((long)(b * 64 + oc) * 24 + oy) * 24 + 2 * ox2;
    out[o] = fmaxf(s0, 0.f);
    out[o + 1] = fmaxf(s1, 0.f);
  }
}

template <int IC, int IH, int IW, int OC, int OH, int OW>
__global__ void convs3(const float* __restrict__ in, const float* __restrict__ w,
                       const float* __restrict__ bias, float* __restrict__ out) {
  const int b = blockIdx.x / OH, oy = blockIdx.x % OH;
  constexpr int PW = 3 * OW;           // padded width; p = ox*3+kx in [0, 3*OW-1]
  constexpr int NT = (OC / 2) * OW;    // threads
  __shared__ __attribute__((aligned(16))) float in_s[8][3][PW];
  __shared__ __attribute__((aligned(16))) float w_s[OC][100];  // [oc][ic*12 + j]
  const int tid = threadIdx.x;
  const int oc = tid / OW, ox = tid % OW;     // oc in 0..OC/2-1
  float s0 = bias[oc], s1 = bias[oc + OC / 2];
  for (int cc = 0; cc < IC; cc += 8) {
    __syncthreads();
    for (int i = tid; i < 8 * 3 * PW; i += NT) {
      int ic = i / (3 * PW), r = (i / PW) % 3, p = i % PW;
      int iy = oy * 3 - 2 + r, ix = p - 2;
      in_s[ic][r][p] = (iy >= 0 && iy < IH && ix >= 0 && ix < IW)
                         ? in[((long)(b * IC + cc + ic) * IH + iy) * IW + ix] : 0.f;
    }
    for (int i = tid; i < OC * 8 * 9; i += NT) {
      int o = i / 72, r = i % 72;
      w_s[o][(r / 9) * 12 + (r % 9)] = w[(long)(o * IC + cc + r / 9) * 9 + r % 9];
    }
    __syncthreads();
    #pragma unroll
    for (int ic = 0; ic < 8; ic++) {
      const float* wr0 = &w_s[oc][ic * 12];
      const float* wr1 = &w_s[oc + OC / 2][ic * 12];
      f32x4 wa = *(const f32x4*)wr0, wb = *(const f32x4*)(wr0 + 4);
      f32x4 va = *(const f32x4*)wr1, vb = *(const f32x4*)(wr1 + 4);
      float wA[9] = {wa[0], wa[1], wa[2], wa[3], wb[0], wb[1], wb[2], wb[3], wr0[8]};
      float wB[9] = {va[0], va[1], va[2], va[3], vb[0], vb[1], vb[2], vb[3], wr1[8]};
      #pragma unroll
      for (int ky = 0; ky < 3; ky++)
        #pragma unroll
        for (int kx = 0; kx < 3; kx++) {
          float iv = in_s[ic][ky][ox * 3 + kx];
          s0 += iv * wA[ky * 3 + kx];
          s1 += iv * wB[ky * 3 + kx];
        }
    }
  }
  out[((long)(b * OC + oc) * OH + oy) * OW + ox] = fmaxf(s0, 0.f);
  out[((long)(b * OC + oc + OC / 2) * OH + oy) * OW + ox] = fmaxf(s1, 0.f);
}

template <int K, int N, bool RELU>
__global__ __launch_bounds__(128) void fc_mfma(const float* __restrict__ A,
                                               const unsigned short* __restrict__ wh,
                                               const unsigned short* __restrict__ wl,
                                               const float* __restrict__ bias,
                                               float* __restrict__ C) {
  const int nb = N / 32;
  const int rb = (blockIdx.x / nb) * 16, cb = (blockIdx.x % nb) * 32;
  __shared__ __attribute__((aligned(16))) short A_hi[16][K + 8];
  __shared__ __attribute__((aligned(16))) short A_lo[16][K + 8];
  const int tid = threadIdx.x;
  const int wv = tid >> 6, lane = tid & 63, n16 = lane & 15, quad = lane >> 4;

  for (int i = tid; i < 16 * (K / 4); i += 128) {
    int row = i / (K / 4), q = i % (K / 4);
    f32x4 v = *(const f32x4*)(A + (long)(rb + row) * K + 4 * q);
    short4_t sh, sl;
    #pragma unroll
    for (int c = 0; c < 4; c++) {
      short hh = f2bf(v[c]); sh[c] = hh; sl[c] = f2bf(v[c] - bf2f(hh));
    }
    *(short4_t*)&A_hi[row][4 * q] = sh;
    *(short4_t*)&A_lo[row][4 * q] = sl;
  }
  __syncthreads();

  const int col = cb + wv * 16 + n16;
  f32x4 a0 = {0.f, 0.f, 0.f, 0.f}, a1 = a0, a2 = a0;
  constexpr int NP = K / 512;
  #pragma unroll 1
  for (int p = 0; p < NP; p++) {
    short8 fh[16], fl[16];
    const unsigned short* wb0 = wh + (long)col * K + p * 512 + quad * 8;
    const unsigned short* wb1 = wl + (long)col * K + p * 512 + quad * 8;
    #pragma unroll
    for (int ks = 0; ks < 16; ks++) {
      fh[ks] = *(const short8*)(wb0 + ks * 32);
      fl[ks] = *(const short8*)(wb1 + ks * 32);
    }
    #pragma unroll
    for (int ks = 0; ks < 16; ks++) {
      short8 ah = *(const short8*)&A_hi[n16][p * 512 + ks * 32 + quad * 8];
      short8 al = *(const short8*)&A_lo[n16][p * 512 + ks * 32 + quad * 8];
      a0 = __builtin_amdgcn_mfma_f32_16x16x32_bf16(ah, fh[ks], a0, 0, 0, 0);
      a1 = __builtin_amdgcn_mfma_f32_16x16x32_bf16(al, fh[ks], a1, 0, 0, 0);
      a2 = __builtin_amdgcn_mfma_f32_16x16x32_bf16(ah, fl[ks], a2, 0, 0, 0);
    }
  }
  const float bv = bias[col];
  #pragma unroll
  for (int r = 0; r < 4; r++) {          // C layout: col=lane&15, row=quad*4+r
    float v = a0[r] + a1[r] + a2[r] + bv;
    if (RELU) v = fmaxf(v, 0.f);
    C[(long)(rb + quad * 4 + r) * N + col] = v;
  }
}

// ==================== persistent GRU ====================
// R14: R4 structure (measured-best 361us: 3 gate-waves, whi/wlo VGPR frags,
// h_hi/h_lo LDS, 192 thr) + SPECULATIVE RELOAD WITH BARRIER FALLBACK:
//  - exchange words are bf16-packed + parity-tagged (R11-verified numerics:
//      w = (bf16_hi << 16) | (bf16_lo & 0xFFFE) | ((nt>>1)&1) )
//  - consumers issue the 22-load coalesced burst IMMEDIATELY (overlapped with
//    tid0's non-returning fetch_add), check tags, block-wide consensus via
//    __syncthreads_or. All-fresh -> proceed (skips the R4 poll+serial reload
//    RT). Any-stale -> tid0 polls the proven R4 counter, then ONLY stale
//    slots re-load once (bounded traffic; no R11 poll storm).
//  - consumer convert is now bit-unpack (producers pre-split bf16).
// hprev carried in elementwise-thread registers (R10-R12-verified).
__global__ __launch_bounds__(192, 1) void gru_k(
    const float* __restrict__ actions, const float* __restrict__ w_ih,
    const float* __restrict__ w_hh, const float* __restrict__ b_ih,
    const float* __restrict__ b_hh, const float* __restrict__ h0,
    float* __restrict__ out, float* __restrict__ hT,
    unsigned* __restrict__ bar, unsigned* __restrict__ xb) {
  const int bg = blockIdx.x >> 5;   // 0..7
  const int hg = blockIdx.x & 31;   // 0..31
  const int tid = threadIdx.x;
  const int wv = tid >> 6;          // gate: 0=r 1=z 2=n
  const int lane = tid & 63;
  const int n16 = lane & 15;
  const int quad = lane >> 4;

  __shared__ short h_hi[16][520];   // +8 pad: 2-way-max LDS banking for b128 reads
  __shared__ short h_lo[16][520];
  __shared__ float act_s[16][2 * TT];
  __shared__ float gh_s[3][16][17];
  __shared__ float bih_s[48], bhh_s[48], wih0_s[48], wih1_s[48];

  // ---- per-lane w_hh B-fragments (resident in VGPRs for the whole kernel) ----
  short8 whi[16], wlo[16];
  {
    const int grow = wv * HID + hg * 16 + n16;
    const float* wr = w_hh + (long)grow * HID + quad * 8;
    #pragma unroll
    for (int ks = 0; ks < 16; ks++) {
      f32x4 v0 = *(const f32x4*)(wr + ks * 32);
      f32x4 v1 = *(const f32x4*)(wr + ks * 32 + 4);
      short8 hi, lo;
      #pragma unroll
      for (int j = 0; j < 4; j++) {
        short h1 = f2bf(v0[j]); hi[j] = h1;     lo[j] = f2bf(v0[j] - bf2f(h1));
        short h2 = f2bf(v1[j]); hi[j + 4] = h2; lo[j + 4] = f2bf(v1[j] - bf2f(h2));
      }
      whi[ks] = hi; wlo[ks] = lo;
    }
  }
  for (int i = tid; i < 48; i += 192) {
    int row = (i >> 4) * HID + hg * 16 + (i & 15);
    bih_s[i] = b_ih[row];
    bhh_s[i] = b_hh[row];
    wih0_s[i] = w_ih[row * 2];
    wih1_s[i] = w_ih[row * 2 + 1];
  }
  for (int i = tid; i < 16 * 2 * TT; i += 192) {
    int m = i / (2 * TT), r = i % (2 * TT);
    act_s[m][r] = actions[(long)(bg * 16 + m) * (2 * TT) + r];
  }
  // h0 -> LDS (bf16 hi/lo)
  for (int i = tid; i < 2048; i += 192) {
    int m = i >> 7, k4 = (i & 127) << 2;
    f32x4 v = *(const f32x4*)(h0 + (long)(bg * 16 + m) * HID + k4);
    short4_t sh, sl;
    #pragma unroll
    for (int c2 = 0; c2 < 4; c2++) {
      short hh = f2bf(v[c2]); sh[c2] = hh; sl[c2] = f2bf(v[c2] - bf2f(hh));
    }
    *(short4_t*)&h_hi[m][k4] = sh;
    *(short4_t*)&h_lo[m][k4] = sl;
  }
  // hprev in registers for the elementwise threads
  float hp0 = 0.f, hp1 = 0.f;
  if (tid < 128) {
    const int m = tid >> 3, n0 = (tid & 7) << 1;
    f32x2 u = *(const f32x2*)(h0 + (long)(bg * 16 + m) * HID + hg * 16 + n0);
    hp0 = u[0]; hp1 = u[1];
  }
  __syncthreads();

  unsigned* my_bar = bar + bg * 32;  // 128B-spaced per-group counters

  #pragma unroll 1
  for (int t = 0; t < TT; t++) {
    // ---- gh (this wave's gate, 16x16 tile): bf16x2 split, 3 acc chains ----
    f32x4 a0 = {0.f, 0.f, 0.f, 0.f}, a1 = a0, a2 = a0;
    #pragma unroll
    for (int ks = 0; ks < 16; ks++) {
      short8 ah = *(const short8*)&h_hi[n16][ks * 32 + quad * 8];
      short8 al = *(const short8*)&h_lo[n16][ks * 32 + quad * 8];
      a0 = __builtin_amdgcn_mfma_f32_16x16x32_bf16(ah, whi[ks], a0, 0, 0, 0);
      a1 = __builtin_amdgcn_mfma_f32_16x16x32_bf16(al, whi[ks], a1, 0, 0, 0);
      a2 = __builtin_amdgcn_mfma_f32_16x16x32_bf16(ah, wlo[ks], a2, 0, 0, 0);
    }
    #pragma unroll
    for (int r = 0; r < 4; r++)            // C layout: col=lane&15, row=quad*4+r
      gh_s[wv][quad * 4 + r][n16] = a0[r] + a1[r] + a2[r];
    __syncthreads();                       // gh_s ready; h LDS free

    const int nt = t + 1;
    const unsigned tagbit = (unsigned)((nt >> 1) & 1);
    unsigned* xcur = xb + (nt & 1) * 65536;     // word plane for h_{t+1}

    // ---- elementwise gates + h update; 128 threads x 2 hidden dims ----
    if (tid < 128) {
      const int m = tid >> 3;
      const int n0 = (tid & 7) << 1;
      const float x0 = act_s[m][2 * t], x1 = act_s[m][2 * t + 1];
      float hy[2];
      #pragma unroll
      for (int q = 0; q < 2; q++) {
        int n = n0 + q;
        float hr = gh_s[0][m][n] + bhh_s[n];
        float hz = gh_s[1][m][n] + bhh_s[16 + n];
        float hn = gh_s[2][m][n] + bhh_s[32 + n];
        float ir = x0 * wih0_s[n]      + x1 * wih1_s[n]      + bih_s[n];
        float iz = x0 * wih0_s[16 + n] + x1 * wih1_s[16 + n] + bih_s[16 + n];
        float in_ = x0 * wih0_s[32 + n] + x1 * wih1_s[32 + n] + bih_s[32 + n];
        float rg = 1.f / (1.f + __expf(-(ir + hr)));
        float zg = 1.f / (1.f + __expf(-(iz + hz)));
        float nx = in_ + rg * hn;
        float ng = 1.f - 2.f / (__expf(2.f * nx) + 1.f);   // tanh
        float hprev = q ? hp1 : hp0;
        hy[q] = ng + zg * (hprev - ng);
      }
      hp0 = hy[0]; hp1 = hy[1];
      ull pack = (ull)__float_as_uint(hy[0]) |
                 ((ull)__float_as_uint(hy[1]) << 32);
      // out is host-only: plain write-back store
      *(ull*)&out[((long)(bg * 16 + m) * TT + t) * HID + hg * 16 + n0] = pack;
      if (t == TT - 1) {
        *(ull*)&hT[(long)(bg * 16 + m) * HID + hg * 16 + n0] = pack;
      } else {
        // packed tagged exchange words (device-coherent 8B store)
        short s0h = f2bf(hy[0]), s1h = f2bf(hy[1]);
        short s0l = f2bf(hy[0] - bf2f(s0h)), s1l = f2bf(hy[1] - bf2f(s1h));
        unsigned w0 = ((unsigned)(unsigned short)s0h << 16) |
                      (((unsigned)(unsigned short)s0l) & 0xFFFEu) | tagbit;
        unsigned w1 = ((unsigned)(unsigned short)s1h << 16) |
                      (((unsigned)(unsigned short)s1l) & 0xFFFEu) | tagbit;
        ull pk = (ull)w0 | ((ull)w1 << 32);
        __hip_atomic_store(
            (ull*)xcur + ((long)bg * 4096 + m * 256 + hg * 8 + (n0 >> 1)),
            pk, __ATOMIC_RELAXED, __HIP_MEMORY_SCOPE_AGENT);
      }
    }
    __syncthreads();   // drains vmcnt(0): exchange stores are device-visible

    if (t < TT - 1) {
      // arrival signal (non-returning atomic; off critical path in happy case)
      if (tid == 0)
        __hip_atomic_fetch_add(my_bar, 1u, __ATOMIC_RELAXED,
                               __HIP_MEMORY_SCOPE_AGENT);
      // ---- speculative burst: 22 coalesced 8B loads, then tag check ----
      const ull* xq = (const ull*)xcur + (long)bg * 4096;
      ull vb[22];
      unsigned stale = 0;
      #pragma unroll
      for (int u = 0; u < 21; u++)
        vb[u] = aload8(xq + tid + u * 192);
      if (tid < 64)
        vb[21] = aload8(xq + 4032 + tid);
      #pragma unroll
      for (int u = 0; u < 21; u++) {
        unsigned lo32 = (unsigned)vb[u], hi32 = (unsigned)(vb[u] >> 32);
        if ((((lo32 ^ tagbit) | (hi32 ^ tagbit)) & 1u) != 0u) stale |= 1u << u;
      }
      if (tid < 64) {
        unsigned lo32 = (unsigned)vb[21], hi32 = (unsigned)(vb[21] >> 32);
        if ((((lo32 ^ tagbit) | (hi32 ^ tagbit)) & 1u) != 0u) stale |= 1u << 21;
      }
      if (__syncthreads_or((int)stale)) {
        // fallback: proven R4 barrier, then re-load ONLY stale slots once
        if (tid == 0) {
          const unsigned target = 32u * (unsigned)(t + 1);
          while (__hip_atomic_load(my_bar, __ATOMIC_RELAXED,
                                   __HIP_MEMORY_SCOPE_AGENT) < target)
            __builtin_amdgcn_s_sleep(1);
        }
        __syncthreads();
        if (stale) {
          #pragma unroll
          for (int u = 0; u < 21; u++)
            if (stale & (1u << u)) vb[u] = aload8(xq + tid + u * 192);
          if ((tid < 64) && (stale & (1u << 21)))
            vb[21] = aload8(xq + 4032 + tid);
        }
      }
      // ---- unpack straight to LDS: 2x b32 writes per 8B chunk ----
      #pragma unroll
      for (int u = 0; u < 21; u++) {
        int c = tid + u * 192;
        int m = c >> 8, j = (c & 255) << 1;
        unsigned lo32 = (unsigned)vb[u], hi32 = (unsigned)(vb[u] >> 32);
        *(unsigned*)&h_hi[m][j] = (lo32 >> 16) | (hi32 & 0xFFFF0000u);
        *(unsigned*)&h_lo[m][j] = (lo32 & 0xFFFEu) | ((hi32 & 0xFFFEu) << 16);
      }
      if (tid < 64) {
        int c = 4032 + tid;
        int m = c >> 8, j = (c & 255) << 1;
        unsigned lo32 = (unsigned)vb[21], hi32 = (unsigned)(vb[21] >> 32);
        *(unsigned*)&h_hi[m][j] = (lo32 >> 16) | (hi32 & 0xFFFF0000u);
        *(unsigned*)&h_lo[m][j] = (lo32 & 0xFFFEu) | ((hi32 & 0xFFFEu) << 16);
      }
      __syncthreads();                     // h LDS settled for next MFMA
    }
  }
}

// ==================== launch ====================
extern "C" void kernel_launch(void* const* d_in, const int* in_sizes, int n_in,
                              void* d_out, int out_size, void* d_ws, size_t ws_size,
                              hipStream_t stream) {
  const float* images  = (const float*)d_in[0];
  const float* actions = (const float*)d_in[1];
  const float* cw1 = (const float*)d_in[2];
  const float* cb1 = (const float*)d_in[3];
  const float* cw2 = (const float*)d_in[4];
  const float* cb2 = (const float*)d_in[5];
  const float* cw3 = (const float*)d_in[6];
  const float* cb3 = (const float*)d_in[7];
  const float* fw1 = (const float*)d_in[8];
  const float* fb1 = (const float*)d_in[9];
  const float* fw2 = (const float*)d_in[10];
  const float* fb2 = (const float*)d_in[11];
  const float* fw3 = (const float*)d_in[12];
  const float* fb3 = (const float*)d_in[13];
  const float* w_ih = (const float*)d_in[14];
  const float* w_hh = (const float*)d_in[15];
  const float* b_ih = (const float*)d_in[16];
  const float* b_hh = (const float*)d_in[17];

  char* ws = (char*)d_ws;
  unsigned* bar = (unsigned*)ws;                 // 1 KB of barrier counters
  float* a1 = (float*)(ws + 1024);               // [128,64,24,24]
  float* a2 = a1 + (long)128 * 64 * 576;         // [128,64,9,9]
  float* a3 = a2 + (long)128 * 64 * 81;          // [128,1024] flat
  float* f1 = a3 + (long)128 * 1024;             // [128,1024]
  float* f2 = f1 + (long)128 * 1024;             // [128,512]
  float* h0 = f2 + (long)128 * 512;              // [128,512]
  // bf16 hi/lo planes of fc weights (filled by wsplit_all):
  unsigned short* wfh1 = (unsigned short*)(h0 + 65536);   // 1024*1024
  unsigned short* wfl1 = wfh1 + (long)1048576;
  unsigned short* wfh2 = wfl1 + (long)1048576;            // 512*1024
  unsigned short* wfl2 = wfh2 + (long)524288;
  unsigned short* wfh3 = wfl2 + (long)524288;             // 512*512
  unsigned short* wfl3 = wfh3 + (long)262144;
  // GRU packed exchange: [2 buf][128][512] 4B words = 512 KB
  unsigned* xb = (unsigned*)(wfl3 + 262144);

  float* out = (float*)d_out;                    // [128,100,512]
  float* hT  = out + (long)BB * TT * HID;        // [128,512]

  hipMemsetAsync(bar, 0, 1024, stream);
  // poison exchange buffers: buf0 parity 0 vs first tag 1; buf1 bytes 0x01
  // -> every word bit0 = 1 vs first tag 0
  hipMemsetAsync(xb, 0x00, 65536 * 4, stream);
  hipMemsetAsync(xb + 65536, 0x01, 65536 * 4, stream);
  wsplit_all<<<448, 256, 0, stream>>>(fw1, fw2, fw3, wfh1, wfl1, wfh2, wfl2,
                                      wfh3, wfl3);
  conv1_k<<<128 * 24, 192, 0, stream>>>(images, cw1, cb1, a1);
  convs3<64, 24, 24, 64, 9, 9><<<128 * 9, 288, 0, stream>>>(a1, cw2, cb2, a2);
  convs3<64, 9, 9, 64, 4, 4><<<128 * 4, 128, 0, stream>>>(a2, cw3, cb3, a3);
  fc_mfma<1024, 1024, true><<<256, 128, 0, stream>>>(a3, wfh1, wfl1, fb1, f1);
  fc_mfma<1024, 512, true><<<128, 128, 0, stream>>>(f1, wfh2, wfl2, fb2, f2);
  fc_mfma<512, 512, false><<<128, 128, 0, stream>>>(f2, wfh3, wfl3, fb3, h0);
  gru_k<<<256, 192, 0, stream>>>(actions, w_ih, w_hh, b_ih, b_hh, h0, out, hT,
                                 bar, xb);
}

// Round 11
// 639.830 us; speedup vs baseline: 1.7264x; 1.1257x over previous
//
#include <hip/hip_runtime.h>
#include <cstdint>

// ---------------- problem constants ----------------
#define BB   128
#define TT   100
#define HID  512

typedef __attribute__((ext_vector_type(4))) float f32x4;
typedef __attribute__((ext_vector_type(2))) float f32x2;
typedef __attribute__((ext_vector_type(8))) short short8;
typedef __attribute__((ext_vector_type(4))) short short4_t;
typedef unsigned long long ull;

__device__ __forceinline__ short f2bf(float x) {            // RNE fp32 -> bf16
  unsigned u = __float_as_uint(x);
  unsigned r = (u + 0x7fffu + ((u >> 16) & 1u)) >> 16;
  return (short)r;
}
__device__ __forceinline__ float bf2f(short s) {
  return __uint_as_float(((unsigned)(unsigned short)s) << 16);
}

// ==================== weight prep: fp32 -> bf16 hi/lo (3 arrays, 1 kernel) ====
__global__ __launch_bounds__(256) void wsplit_all(
    const float* __restrict__ w1, const float* __restrict__ w2,
    const float* __restrict__ w3, unsigned short* __restrict__ h1,
    unsigned short* __restrict__ l1, unsigned short* __restrict__ h2,
    unsigned short* __restrict__ l2, unsigned short* __restrict__ h3,
    unsigned short* __restrict__ l3) {
  int i = blockIdx.x * 256 + threadIdx.x;
  const int stride = gridDim.x * 256;
  for (; i < 458752; i += stride) {
    const float* src; unsigned short *ph, *pl; int j;
    if (i < 262144)      { src = w1; ph = h1; pl = l1; j = i; }
    else if (i < 393216) { src = w2; ph = h2; pl = l2; j = i - 262144; }
    else                 { src = w3; ph = h3; pl = l3; j = i - 393216; }
    f32x4 v = *(const f32x4*)(src + 4 * (long)j);
    short4_t h, l;
    #pragma unroll
    for (int c = 0; c < 4; c++) {
      short hh = f2bf(v[c]); h[c] = hh; l[c] = f2bf(v[c] - bf2f(hh));
    }
    *(short4_t*)(ph + 4 * (long)j) = h;
    *(short4_t*)(pl + 4 * (long)j) = l;
  }
}

// ==================== encoder (R9, measured-best) ====================

__global__ __launch_bounds__(192) void conv1_k(const float* __restrict__ in,
                                               const float* __restrict__ w,
                                               const float* __restrict__ bias,
                                               float* __restrict__ out) {
  const int b = blockIdx.x / 24, oy = blockIdx.x % 24;
  __shared__ __attribute__((aligned(16))) float in_s[3][5][76]; // p = ix+2
  __shared__ __attribute__((aligned(16))) float ws[64][76];     // padded rows
  const int tid = threadIdx.x;
  for (int i = tid; i < 3 * 5 * 76; i += 192) {
    int ic = i / 380, rem = i % 380, r = rem / 76, p = rem % 76;
    int iy = oy * 3 + r - 2, ix = p - 2;
    in_s[ic][r][p] = (iy >= 0 && iy < 72 && ix >= 0 && ix < 72)
                       ? in[((long)(b * 3 + ic) * 72 + iy) * 72 + ix] : 0.f;
  }
  for (int i = tid; i < 64 * 75; i += 192) ws[i / 75][i % 75] = w[i];
  __syncthreads();

  const int ox2 = tid % 12;           // ox pair: ox = 2*ox2, 2*ox2+1
  const int og = tid / 12;            // 0..15
  float strip[15][8];
  #pragma unroll
  for (int ic = 0; ic < 3; ic++)
    #pragma unroll
    for (int ky = 0; ky < 5; ky++) {
      const float* bp = &in_s[ic][ky][6 * ox2];
      #pragma unroll
      for (int h = 0; h < 4; h++) {
        f32x2 u = *(const f32x2*)(bp + 2 * h);
        strip[ic * 5 + ky][2 * h] = u[0];
        strip[ic * 5 + ky][2 * h + 1] = u[1];
      }
    }

  #pragma unroll
  for (int j = 0; j < 4; j++) {
    const int oc = og + 16 * j;
    float s0 = bias[oc], s1 = bias[oc];
    const float* wrow = ws[oc];
    #pragma unroll
    for (int k4 = 0; k4 < 18; k4++) {
      f32x4 wq = *(const f32x4*)(wrow + 4 * k4);
      #pragma unroll
      for (int q = 0; q < 4; q++) {
        const int k = 4 * k4 + q, i5 = k / 5, kx = k % 5;
        s0 += strip[i5][kx] * wq[q];
        s1 += strip[i5][kx + 3] * wq[q];
      }
    }
    s0 += strip[14][2] * wrow[72]; s1 += strip[14][5] * wrow[72];
    s0 += strip[14][3] * wrow[73]; s1 += strip[14][6] * wrow[73];
    s0 += strip[14][4] * wrow[74]; s1 += strip[14][7] * wrow[74];
    long o = ((long)(b * 64 + oc) * 24 + oy) * 24 + 2 * ox2;
    out[o] = fmaxf(s0, 0.f);
    out[o + 1] = fmaxf(s1, 0.f);
  }
}

template <int IC, int IH, int IW, int OC, int OH, int OW>
__global__ void convs3(const float* __restrict__ in, const float* __restrict__ w,
                       const float* __restrict__ bias, float* __restrict__ out) {
  const int b = blockIdx.x / OH, oy = blockIdx.x % OH;
  constexpr int PW = 3 * OW;           // padded width; p = ox*3+kx in [0, 3*OW-1]
  constexpr int NT = (OC / 2) * OW;    // threads
  __shared__ __attribute__((aligned(16))) float in_s[8][3][PW];
  __shared__ __attribute__((aligned(16))) float w_s[OC][100];  // [oc][ic*12 + j]
  const int tid = threadIdx.x;
  const int oc = tid / OW, ox = tid % OW;     // oc in 0..OC/2-1
  float s0 = bias[oc], s1 = bias[oc + OC / 2];
  for (int cc = 0; cc < IC; cc += 8) {
    __syncthreads();
    for (int i = tid; i < 8 * 3 * PW; i += NT) {
      int ic = i / (3 * PW), r = (i / PW) % 3, p = i % PW;
      int iy = oy * 3 - 2 + r, ix = p - 2;
      in_s[ic][r][p] = (iy >= 0 && iy < IH && ix >= 0 && ix < IW)
                         ? in[((long)(b * IC + cc + ic) * IH + iy) * IW + ix] : 0.f;
    }
    for (int i = tid; i < OC * 8 * 9; i += NT) {
      int o = i / 72, r = i % 72;
      w_s[o][(r / 9) * 12 + (r % 9)] = w[(long)(o * IC + cc + r / 9) * 9 + r % 9];
    }
    __syncthreads();
    #pragma unroll
    for (int ic = 0; ic < 8; ic++) {
      const float* wr0 = &w_s[oc][ic * 12];
      const float* wr1 = &w_s[oc + OC / 2][ic * 12];
      f32x4 wa = *(const f32x4*)wr0, wb = *(const f32x4*)(wr0 + 4);
      f32x4 va = *(const f32x4*)wr1, vb = *(const f32x4*)(wr1 + 4);
      float wA[9] = {wa[0], wa[1], wa[2], wa[3], wb[0], wb[1], wb[2], wb[3], wr0[8]};
      float wB[9] = {va[0], va[1], va[2], va[3], vb[0], vb[1], vb[2], vb[3], wr1[8]};
      #pragma unroll
      for (int ky = 0; ky < 3; ky++)
        #pragma unroll
        for (int kx = 0; kx < 3; kx++) {
          float iv = in_s[ic][ky][ox * 3 + kx];
          s0 += iv * wA[ky * 3 + kx];
          s1 += iv * wB[ky * 3 + kx];
        }
    }
  }
  out[((long)(b * OC + oc) * OH + oy) * OW + ox] = fmaxf(s0, 0.f);
  out[((long)(b * OC + oc + OC / 2) * OH + oy) * OW + ox] = fmaxf(s1, 0.f);
}

template <int K, int N, bool RELU>
__global__ __launch_bounds__(128) void fc_mfma(const float* __restrict__ A,
                                               const unsigned short* __restrict__ wh,
                                               const unsigned short* __restrict__ wl,
                                               const float* __restrict__ bias,
                                               float* __restrict__ C) {
  const int nb = N / 32;
  const int rb = (blockIdx.x / nb) * 16, cb = (blockIdx.x % nb) * 32;
  __shared__ __attribute__((aligned(16))) short A_hi[16][K + 8];
  __shared__ __attribute__((aligned(16))) short A_lo[16][K + 8];
  const int tid = threadIdx.x;
  const int wv = tid >> 6, lane = tid & 63, n16 = lane & 15, quad = lane >> 4;

  for (int i = tid; i < 16 * (K / 4); i += 128) {
    int row = i / (K / 4), q = i % (K / 4);
    f32x4 v = *(const f32x4*)(A + (long)(rb + row) * K + 4 * q);
    short4_t sh, sl;
    #pragma unroll
    for (int c = 0; c < 4; c++) {
      short hh = f2bf(v[c]); sh[c] = hh; sl[c] = f2bf(v[c] - bf2f(hh));
    }
    *(short4_t*)&A_hi[row][4 * q] = sh;
    *(short4_t*)&A_lo[row][4 * q] = sl;
  }
  __syncthreads();

  const int col = cb + wv * 16 + n16;
  f32x4 a0 = {0.f, 0.f, 0.f, 0.f}, a1 = a0, a2 = a0;
  constexpr int NP = K / 512;
  #pragma unroll 1
  for (int p = 0; p < NP; p++) {
    short8 fh[16], fl[16];
    const unsigned short* wb0 = wh + (long)col * K + p * 512 + quad * 8;
    const unsigned short* wb1 = wl + (long)col * K + p * 512 + quad * 8;
    #pragma unroll
    for (int ks = 0; ks < 16; ks++) {
      fh[ks] = *(const short8*)(wb0 + ks * 32);
      fl[ks] = *(const short8*)(wb1 + ks * 32);
    }
    #pragma unroll
    for (int ks = 0; ks < 16; ks++) {
      short8 ah = *(const short8*)&A_hi[n16][p * 512 + ks * 32 + quad * 8];
      short8 al = *(const short8*)&A_lo[n16][p * 512 + ks * 32 + quad * 8];
      a0 = __builtin_amdgcn_mfma_f32_16x16x32_bf16(ah, fh[ks], a0, 0, 0, 0);
      a1 = __builtin_amdgcn_mfma_f32_16x16x32_bf16(al, fh[ks], a1, 0, 0, 0);
      a2 = __builtin_amdgcn_mfma_f32_16x16x32_bf16(ah, fl[ks], a2, 0, 0, 0);
    }
  }
  const float bv = bias[col];
  #pragma unroll
  for (int r = 0; r < 4; r++) {          // C layout: col=lane&15, row=quad*4+r
    float v = a0[r] + a1[r] + a2[r] + bv;
    if (RELU) v = fmaxf(v, 0.f);
    C[(long)(rb + quad * 4 + r) * N + col] = v;
  }
}

// ==================== persistent GRU ====================
// R15: EXACT R4 structure (measured 361us x3: 3 gate-waves, whi/wlo VGPR
// frags, h_hi/h_lo LDS, fp32 h exchange through `out` with agent-scope
// stores, fetch_add barrier, coalesced 22x8B reload + consumer convert).
// Only verified delta: hprev carried in elementwise-thread registers
// (R10-R14-verified; absmax 0.00098, removes 2 LDS reads/step).
// After 7 failed exchange restructures (R5/R6/R10/R11/R13/R14), this
// exchange is established as the local optimum — do not mutate further.
__global__ __launch_bounds__(192, 1) void gru_k(
    const float* __restrict__ actions, const float* __restrict__ w_ih,
    const float* __restrict__ w_hh, const float* __restrict__ b_ih,
    const float* __restrict__ b_hh, const float* __restrict__ h0,
    float* __restrict__ out, float* __restrict__ hT, unsigned* __restrict__ bar) {
  const int bg = blockIdx.x >> 5;   // 0..7
  const int hg = blockIdx.x & 31;   // 0..31
  const int tid = threadIdx.x;
  const int wv = tid >> 6;          // gate: 0=r 1=z 2=n
  const int lane = tid & 63;
  const int n16 = lane & 15;
  const int quad = lane >> 4;

  __shared__ short h_hi[16][520];   // +8 pad: 2-way-max LDS banking for b128 reads
  __shared__ short h_lo[16][520];
  __shared__ float act_s[16][2 * TT];
  __shared__ float gh_s[3][16][17];
  __shared__ float bih_s[48], bhh_s[48], wih0_s[48], wih1_s[48];

  // ---- per-lane w_hh B-fragments (resident in VGPRs for the whole kernel) ----
  short8 whi[16], wlo[16];
  {
    const int grow = wv * HID + hg * 16 + n16;
    const float* wr = w_hh + (long)grow * HID + quad * 8;
    #pragma unroll
    for (int ks = 0; ks < 16; ks++) {
      f32x4 v0 = *(const f32x4*)(wr + ks * 32);
      f32x4 v1 = *(const f32x4*)(wr + ks * 32 + 4);
      short8 hi, lo;
      #pragma unroll
      for (int j = 0; j < 4; j++) {
        short h1 = f2bf(v0[j]); hi[j] = h1;     lo[j] = f2bf(v0[j] - bf2f(h1));
        short h2 = f2bf(v1[j]); hi[j + 4] = h2; lo[j + 4] = f2bf(v1[j] - bf2f(h2));
      }
      whi[ks] = hi; wlo[ks] = lo;
    }
  }
  for (int i = tid; i < 48; i += 192) {
    int row = (i >> 4) * HID + hg * 16 + (i & 15);
    bih_s[i] = b_ih[row];
    bhh_s[i] = b_hh[row];
    wih0_s[i] = w_ih[row * 2];
    wih1_s[i] = w_ih[row * 2 + 1];
  }
  for (int i = tid; i < 16 * 2 * TT; i += 192) {
    int m = i / (2 * TT), r = i % (2 * TT);
    act_s[m][r] = actions[(long)(bg * 16 + m) * (2 * TT) + r];
  }
  // h0 -> LDS (bf16 hi/lo)
  for (int i = tid; i < 2048; i += 192) {
    int m = i >> 7, k4 = (i & 127) << 2;
    f32x4 v = *(const f32x4*)(h0 + (long)(bg * 16 + m) * HID + k4);
    short4_t sh, sl;
    #pragma unroll
    for (int c2 = 0; c2 < 4; c2++) {
      short hh = f2bf(v[c2]); sh[c2] = hh; sl[c2] = f2bf(v[c2] - bf2f(hh));
    }
    *(short4_t*)&h_hi[m][k4] = sh;
    *(short4_t*)&h_lo[m][k4] = sl;
  }
  // hprev in registers for the elementwise threads
  float hp0 = 0.f, hp1 = 0.f;
  if (tid < 128) {
    const int m = tid >> 3, n0 = (tid & 7) << 1;
    f32x2 u = *(const f32x2*)(h0 + (long)(bg * 16 + m) * HID + hg * 16 + n0);
    hp0 = u[0]; hp1 = u[1];
  }
  __syncthreads();

  unsigned* my_bar = bar + bg * 32;  // 128B-spaced per-group counters

  #pragma unroll 1
  for (int t = 0; t < TT; t++) {
    // gh (this wave's gate, 16x16 tile): bf16x2 split, 3 independent acc chains
    f32x4 a0 = {0.f, 0.f, 0.f, 0.f}, a1 = a0, a2 = a0;
    #pragma unroll
    for (int ks = 0; ks < 16; ks++) {
      short8 ah = *(const short8*)&h_hi[n16][ks * 32 + quad * 8];
      short8 al = *(const short8*)&h_lo[n16][ks * 32 + quad * 8];
      a0 = __builtin_amdgcn_mfma_f32_16x16x32_bf16(ah, whi[ks], a0, 0, 0, 0);
      a1 = __builtin_amdgcn_mfma_f32_16x16x32_bf16(al, whi[ks], a1, 0, 0, 0);
      a2 = __builtin_amdgcn_mfma_f32_16x16x32_bf16(ah, wlo[ks], a2, 0, 0, 0);
    }
    #pragma unroll
    for (int r = 0; r < 4; r++)            // C layout: col=lane&15, row=quad*4+r
      gh_s[wv][quad * 4 + r][n16] = a0[r] + a1[r] + a2[r];
    __syncthreads();

    // elementwise gates + h update; 128 threads x 2 hidden dims, 8B packed store
    if (tid < 128) {
      const int m = tid >> 3;
      const int n0 = (tid & 7) << 1;
      const float x0 = act_s[m][2 * t], x1 = act_s[m][2 * t + 1];
      float hy[2];
      #pragma unroll
      for (int q = 0; q < 2; q++) {
        int n = n0 + q;
        float hr = gh_s[0][m][n] + bhh_s[n];
        float hz = gh_s[1][m][n] + bhh_s[16 + n];
        float hn = gh_s[2][m][n] + bhh_s[32 + n];
        float ir = x0 * wih0_s[n]      + x1 * wih1_s[n]      + bih_s[n];
        float iz = x0 * wih0_s[16 + n] + x1 * wih1_s[16 + n] + bih_s[16 + n];
        float in_ = x0 * wih0_s[32 + n] + x1 * wih1_s[32 + n] + bih_s[32 + n];
        float rg = 1.f / (1.f + __expf(-(ir + hr)));
        float zg = 1.f / (1.f + __expf(-(iz + hz)));
        float nx = in_ + rg * hn;
        float ng = 1.f - 2.f / (__expf(2.f * nx) + 1.f);   // tanh
        float hprev = q ? hp1 : hp0;
        hy[q] = ng + zg * (hprev - ng);
      }
      hp0 = hy[0]; hp1 = hy[1];
      ull pack = (ull)__float_as_uint(hy[0]) |
                 ((ull)__float_as_uint(hy[1]) << 32);
      // device-coherent packed store (bypasses non-coherent L1/L2)
      __hip_atomic_store(
          (ull*)&out[((long)(bg * 16 + m) * TT + t) * HID + hg * 16 + n0],
          pack, __ATOMIC_RELAXED, __HIP_MEMORY_SCOPE_AGENT);
      if (t == TT - 1)
        *(ull*)&hT[(long)(bg * 16 + m) * HID + hg * 16 + n0] = pack;
    }
    __syncthreads();   // drains vmcnt(0): slice stores are device-visible

    if (t < TT - 1) {
      if (tid == 0) {
        const unsigned target = 32u * (unsigned)(t + 1);
        unsigned prev = __hip_atomic_fetch_add(my_bar, 1u, __ATOMIC_RELAXED,
                                               __HIP_MEMORY_SCOPE_AGENT);
        if (prev + 1u < target) {
          while (__hip_atomic_load(my_bar, __ATOMIC_RELAXED,
                                   __HIP_MEMORY_SCOPE_AGENT) < target)
            __builtin_amdgcn_s_sleep(1);
        }
      }
      __syncthreads();
      // ---- pipelined reload: 21 uniform 8B loads/thread + wave-0 tail ----
      ull vbuf[22];
      #pragma unroll
      for (int u = 0; u < 21; u++) {
        int i = tid + u * 192;
        int m = i >> 8, j = (i & 255) << 1;
        vbuf[u] = __hip_atomic_load(
            (const ull*)(out + ((long)(bg * 16 + m) * TT + t) * HID + j),
            __ATOMIC_RELAXED, __HIP_MEMORY_SCOPE_AGENT);
      }
      if (tid < 64) {
        int i = 4032 + tid;
        int m = i >> 8, j = (i & 255) << 1;
        vbuf[21] = __hip_atomic_load(
            (const ull*)(out + ((long)(bg * 16 + m) * TT + t) * HID + j),
            __ATOMIC_RELAXED, __HIP_MEMORY_SCOPE_AGENT);
      }
      #pragma unroll
      for (int u = 0; u < 21; u++) {
        int i = tid + u * 192;
        int m = i >> 8, j = (i & 255) << 1;
        ull v = vbuf[u];
        float f0 = __uint_as_float((unsigned)v);
        float f1 = __uint_as_float((unsigned)(v >> 32));
        short s0 = f2bf(f0);
        h_hi[m][j] = s0; h_lo[m][j] = f2bf(f0 - bf2f(s0));
        short s1 = f2bf(f1);
        h_hi[m][j + 1] = s1; h_lo[m][j + 1] = f2bf(f1 - bf2f(s1));
      }
      if (tid < 64) {
        int i = 4032 + tid;
        int m = i >> 8, j = (i & 255) << 1;
        ull v = vbuf[21];
        float f0 = __uint_as_float((unsigned)v);
        float f1 = __uint_as_float((unsigned)(v >> 32));
        short s0 = f2bf(f0);
        h_hi[m][j] = s0; h_lo[m][j] = f2bf(f0 - bf2f(s0));
        short s1 = f2bf(f1);
        h_hi[m][j + 1] = s1; h_lo[m][j + 1] = f2bf(f1 - bf2f(s1));
      }
      __syncthreads();
    }
  }
}

// ==================== launch ====================
extern "C" void kernel_launch(void* const* d_in, const int* in_sizes, int n_in,
                              void* d_out, int out_size, void* d_ws, size_t ws_size,
                              hipStream_t stream) {
  const float* images  = (const float*)d_in[0];
  const float* actions = (const float*)d_in[1];
  const float* cw1 = (const float*)d_in[2];
  const float* cb1 = (const float*)d_in[3];
  const float* cw2 = (const float*)d_in[4];
  const float* cb2 = (const float*)d_in[5];
  const float* cw3 = (const float*)d_in[6];
  const float* cb3 = (const float*)d_in[7];
  const float* fw1 = (const float*)d_in[8];
  const float* fb1 = (const float*)d_in[9];
  const float* fw2 = (const float*)d_in[10];
  const float* fb2 = (const float*)d_in[11];
  const float* fw3 = (const float*)d_in[12];
  const float* fb3 = (const float*)d_in[13];
  const float* w_ih = (const float*)d_in[14];
  const float* w_hh = (const float*)d_in[15];
  const float* b_ih = (const float*)d_in[16];
  const float* b_hh = (const float*)d_in[17];

  char* ws = (char*)d_ws;
  unsigned* bar = (unsigned*)ws;                 // 1 KB of barrier counters
  float* a1 = (float*)(ws + 1024);               // [128,64,24,24]
  float* a2 = a1 + (long)128 * 64 * 576;         // [128,64,9,9]
  float* a3 = a2 + (long)128 * 64 * 81;          // [128,1024] flat
  float* f1 = a3 + (long)128 * 1024;             // [128,1024]
  float* f2 = f1 + (long)128 * 1024;             // [128,512]
  float* h0 = f2 + (long)128 * 512;              // [128,512]
  // bf16 hi/lo planes of fc weights (filled by wsplit_all):
  unsigned short* wfh1 = (unsigned short*)(h0 + 65536);   // 1024*1024
  unsigned short* wfl1 = wfh1 + (long)1048576;
  unsigned short* wfh2 = wfl1 + (long)1048576;            // 512*1024
  unsigned short* wfl2 = wfh2 + (long)524288;
  unsigned short* wfh3 = wfl2 + (long)524288;             // 512*512
  unsigned short* wfl3 = wfh3 + (long)262144;

  float* out = (float*)d_out;                    // [128,100,512]
  float* hT  = out + (long)BB * TT * HID;        // [128,512]

  hipMemsetAsync(bar, 0, 1024, stream);
  wsplit_all<<<448, 256, 0, stream>>>(fw1, fw2, fw3, wfh1, wfl1, wfh2, wfl2,
                                      wfh3, wfl3);
  conv1_k<<<128 * 24, 192, 0, stream>>>(images, cw1, cb1, a1);
  convs3<64, 24, 24, 64, 9, 9><<<128 * 9, 288, 0, stream>>>(a1, cw2, cb2, a2);
  convs3<64, 9, 9, 64, 4, 4><<<128 * 4, 128, 0, stream>>>(a2, cw3, cb3, a3);
  fc_mfma<1024, 1024, true><<<256, 128, 0, stream>>>(a3, wfh1, wfl1, fb1, f1);
  fc_mfma<1024, 512, true><<<128, 128, 0, stream>>>(f1, wfh2, wfl2, fb2, f2);
  fc_mfma<512, 512, false><<<128, 128, 0, stream>>>(f2, wfh3, wfl3, fb3, h0);
  gru_k<<<256, 192, 0, stream>>>(actions, w_ih, w_hh, b_ih, b_hh, h0, out, hT, bar);
}